// Round 1
// baseline (682.891 us; speedup 1.0000x reference)
//
#include <hip/hip_runtime.h>

// x: (B=64, L=4096, F=256) fp32
// out = [ d : (64, 4095, 256) ][ y : (64, 4095, 256) ]  flat fp32
//   d[b,l,f] = x[b,l+1,f] - x[b,l,f]
//   y[b,l,f] = x[b,l+1,f] - x[b,0,f]   (l < 4094);  y[b,4094,f] = 0
// (cumsum telescopes -- no scan needed; pure streaming kernel)

constexpr int B    = 64;
constexpr int L    = 4096;
constexpr int F    = 256;
constexpr int F4   = F / 4;    // 64 float4 per row
constexpr int LOUT = L - 1;    // 4095 output rows
constexpr int ROWS = 16;       // rows per thread (register-carried prev)

__global__ __launch_bounds__(256)
void invdiff_kernel(const float* __restrict__ x, float* __restrict__ out) {
    const int tid = threadIdx.x;
    const int f4  = tid & 63;        // one wave = one full row of float4s (coalesced 1KiB)
    const int sub = tid >> 6;        // 4 waves per block -> 4 row-chunks
    const int b   = blockIdx.x >> 6; // 64 blocks per batch
    const int cb  = blockIdx.x & 63;
    const int chunk = cb * 4 + sub;  // 0..255
    const int r0    = chunk * ROWS;  // 0, 16, ..., 4080

    const float4* xb = (const float4*)(x + (size_t)b * L * F) + f4;
    float4* dout = (float4*)out + (size_t)b * LOUT * F4 + f4;
    float4* yout = (float4*)out + ((size_t)B * LOUT + (size_t)b * LOUT) * F4 + f4;

    const float4 x0 = xb[0];                       // L2-resident (64 KiB total)
    float4 prev = xb[(size_t)r0 * F4];
    const int nrows = min(ROWS, LOUT - r0);        // last chunk: 15 rows

    #pragma unroll 4
    for (int i = 0; i < nrows; ++i) {
        const int l = r0 + i;
        const float4 cur = xb[(size_t)(l + 1) * F4];
        float4 d, yv;
        d.x = cur.x - prev.x; d.y = cur.y - prev.y;
        d.z = cur.z - prev.z; d.w = cur.w - prev.w;
        if (l == LOUT - 1) {
            yv = make_float4(0.f, 0.f, 0.f, 0.f);  // reference pads last row with zeros
        } else {
            yv.x = cur.x - x0.x; yv.y = cur.y - x0.y;
            yv.z = cur.z - x0.z; yv.w = cur.w - x0.w;
        }
        dout[(size_t)l * F4] = d;
        yout[(size_t)l * F4] = yv;
        prev = cur;
    }
}

extern "C" void kernel_launch(void* const* d_in, const int* in_sizes, int n_in,
                              void* d_out, int out_size, void* d_ws, size_t ws_size,
                              hipStream_t stream) {
    const float* x = (const float*)d_in[0];
    float* out = (float*)d_out;
    // grid: 64 batches x 64 blocks, 256 threads (4 waves x 16 rows = 64 rows/block)
    invdiff_kernel<<<dim3(B * 64), dim3(256), 0, stream>>>(x, out);
}

// Round 2
// 674.058 us; speedup vs baseline: 1.0131x; 1.0131x over previous
//
#include <hip/hip_runtime.h>

// x: (B=64, L=4096, F=256) fp32
// out = [ d : (64, 4095, 256) ][ y : (64, 4095, 256) ]  flat fp32
//   d[b,l,f] = x[b,l+1,f] - x[b,l,f]
//   y[b,l,f] = x[b,l+1,f] - x[b,0,f]   (l < 4094);  y[b,4094,f] = 0
// (cumsum telescopes -- closed form, pure streaming kernel)
//
// R1 post-mortem: kernel itself <338us (absent from rocprof top-5; dur_us=683
// is dominated by harness 0xAA poison fills, 2GiB @6.3TB/s). This round:
// ROWS 16->32 (read amplification 6%->3%) + non-temporal loads/stores for the
// streaming d/y/x traffic (x0 row stays cached: reused by 128 blocks/batch).

typedef float v4f __attribute__((ext_vector_type(4)));

constexpr int B    = 64;
constexpr int L    = 4096;
constexpr int F    = 256;
constexpr int F4   = F / 4;    // 64 float4 per row
constexpr int LOUT = L - 1;    // 4095 output rows
constexpr int ROWS = 32;       // rows per thread (register-carried prev)

__global__ __launch_bounds__(256)
void invdiff_kernel(const float* __restrict__ x, float* __restrict__ out) {
    const int tid = threadIdx.x;
    const int f4  = tid & 63;        // one wave = one full 1KiB row (coalesced)
    const int sub = tid >> 6;        // 4 waves per block
    const int b   = blockIdx.x >> 5; // 32 blocks per batch
    const int cb  = blockIdx.x & 31;
    const int chunk = cb * 4 + sub;  // 0..127
    const int r0    = chunk * ROWS;  // 0, 32, ..., 4064

    const v4f* xb = (const v4f*)(x + (size_t)b * L * F) + f4;
    v4f* dout = (v4f*)out + (size_t)b * LOUT * F4 + f4;
    v4f* yout = (v4f*)out + ((size_t)B * LOUT + (size_t)b * LOUT) * F4 + f4;

    const v4f x0 = xb[0];            // cached: reused by all blocks of batch b
    v4f prev = __builtin_nontemporal_load(&xb[(size_t)r0 * F4]);
    const int nrows = min(ROWS, LOUT - r0);   // last chunk: 31 rows
    const v4f zero = {0.f, 0.f, 0.f, 0.f};

    #pragma unroll 4
    for (int i = 0; i < nrows; ++i) {
        const int l = r0 + i;
        const v4f cur = __builtin_nontemporal_load(&xb[(size_t)(l + 1) * F4]);
        const v4f d  = cur - prev;
        const v4f yv = (l == LOUT - 1) ? zero : cur - x0;
        __builtin_nontemporal_store(d,  &dout[(size_t)l * F4]);
        __builtin_nontemporal_store(yv, &yout[(size_t)l * F4]);
        prev = cur;
    }
}

extern "C" void kernel_launch(void* const* d_in, const int* in_sizes, int n_in,
                              void* d_out, int out_size, void* d_ws, size_t ws_size,
                              hipStream_t stream) {
    const float* x = (const float*)d_in[0];
    float* out = (float*)d_out;
    // grid: 64 batches x 32 blocks, 256 threads (4 waves x 32 rows = 128 rows/block)
    invdiff_kernel<<<dim3(B * 32), dim3(256), 0, stream>>>(x, out);
}